// Round 3
// baseline (345.933 us; speedup 1.0000x reference)
//
#include <hip/hip_runtime.h>

typedef _Float16 half8  __attribute__((ext_vector_type(8)));
typedef float    floatx4 __attribute__((ext_vector_type(4)));

#define N_NODES 50000
#define N_EDGES 800000
#define SLOPE 0.05f
#define GRID 512
#define NT 3125              // 800000 / 256 edge-tiles

// ---- workspace layout (bytes) ----
#define WS_Z   0ull
#define WS_W1  (WS_Z  + (size_t)N_NODES * 128 * 2)
#define WS_W2  (WS_W1 + 128 * 128 * 2)
#define WS_B0  (WS_W2 + 64 * 128 * 2)
#define WS_B1  (WS_B0 + 128 * 4)
#define WS_B2  (WS_B1 + 128 * 4)
#define WS_W0T (WS_B2 + 64 * 4)          // fp16 [128][64]  W0T[n][k] = W0[k][n]

#define W0_STRIDE 72    // 64 + 8 fp16 pad (16B-aligned rows, 2-way-free banks)
#define H_STRIDE 136    // 128 + 8 fp16 pad
#define HC_STRIDE 40    // 32 + 8 fp16 pad

__device__ __forceinline__ float leaky(float t) { return t >= 0.f ? t : SLOPE * t; }

// ---------------- kernel 1: weight transpose + fp16 convert ----------------
__global__ void wprep_kernel(const float* __restrict__ W0, const float* __restrict__ W1,
                             const float* __restrict__ W2, const float* __restrict__ b0,
                             const float* __restrict__ b1, const float* __restrict__ b2,
                             unsigned char* __restrict__ ws) {
    _Float16* wt1 = (_Float16*)(ws + WS_W1);
    _Float16* wt2 = (_Float16*)(ws + WS_W2);
    _Float16* w0t = (_Float16*)(ws + WS_W0T);
    float* B0 = (float*)(ws + WS_B0);
    float* B1 = (float*)(ws + WS_B1);
    float* B2 = (float*)(ws + WS_B2);
    int t = blockIdx.x * 1024 + threadIdx.x;
    if (t < 16384) {                       // W1 [128][128] -> Wt1[n][k]
        int k = t >> 7, n = t & 127;
        wt1[n * 128 + k] = (_Float16)W1[k * 128 + n];
    } else if (t < 24576) {                // W2 [128][64] -> Wt2[n][k]
        int i = t - 16384;
        int k = i >> 6, n = i & 63;
        wt2[n * 128 + k] = (_Float16)W2[k * 64 + n];
    } else if (t < 32768) {                // W0 [64][128] -> W0T[n][k]
        int i = t - 24576;
        int n = i >> 6, k = i & 63;
        w0t[n * 64 + k] = (_Float16)W0[k * 128 + n];
    } else if (t < 32768 + 320) {
        int i = t - 32768;
        if (i < 128) B0[i] = b0[i];
        else if (i < 256) B1[i - 128] = b1[i - 128];
        else B2[i - 256] = b2[i - 256];
    }
}

// ---------------- kernel 2: z = x @ W0  (fp16 out, no bias/act) ----------------
__global__ __launch_bounds__(512, 4) void z_kernel(const float* __restrict__ x,
                                                   unsigned char* __restrict__ ws) {
    __shared__ __align__(16) _Float16 w0s[128 * W0_STRIDE];
    __shared__ __align__(16) _Float16 hbuf[8][16 * H_STRIDE];
    _Float16* __restrict__ z = (_Float16*)(ws + WS_Z);
    const _Float16* __restrict__ w0t = (const _Float16*)(ws + WS_W0T);

    {   // stage pre-transposed fp16 W0T: 1024 half8 chunks, 2 per thread
        int t = threadIdx.x;
        #pragma unroll
        for (int it = 0; it < 2; ++it) {
            int c = t + it * 512;
            int row = c >> 3, cc = c & 7;
            *(half8*)&w0s[row * W0_STRIDE + cc * 8] = *(const half8*)&w0t[row * 64 + cc * 8];
        }
    }
    __syncthreads();

    const int wave = threadIdx.x >> 6, lane = threadIdx.x & 63;
    const int cl = lane & 15, q = lane >> 4;
    const int rowbase = blockIdx.x * 128 + wave * 16;
    int row = rowbase + cl; if (row > N_NODES - 1) row = N_NODES - 1;

    // A-frags straight from x rows: A[m=lane&15][k=quad*8+j]
    half8 a[2];
    #pragma unroll
    for (int ks = 0; ks < 2; ++ks) {
        const floatx4* px = (const floatx4*)(x + (size_t)row * 64 + ks * 32 + q * 8);
        floatx4 u0 = px[0], u1 = px[1];
        #pragma unroll
        for (int j = 0; j < 4; ++j) { a[ks][j] = (_Float16)u0[j]; a[ks][4 + j] = (_Float16)u1[j]; }
    }

    _Float16* hs = &hbuf[wave][0];
    #pragma unroll
    for (int n = 0; n < 8; ++n) {
        floatx4 c = {0.f, 0.f, 0.f, 0.f};
        #pragma unroll
        for (int ks = 0; ks < 2; ++ks) {
            half8 b = *(const half8*)&w0s[(n * 16 + cl) * W0_STRIDE + ks * 32 + q * 8];
            c = __builtin_amdgcn_mfma_f32_16x16x32_f16(a[ks], b, c, 0, 0, 0);
        }
        #pragma unroll
        for (int r = 0; r < 4; ++r)   // C/D: col=lane&15, row=quad*4+reg
            hs[(q * 4 + r) * H_STRIDE + n * 16 + cl] = (_Float16)c[r];
    }

    int rl = lane >> 2, ch = lane & 3;
    int grow = rowbase + rl;
    if (grow < N_NODES) {
        #pragma unroll
        for (int i = 0; i < 4; ++i)
            *(half8*)(z + (size_t)grow * 128 + i * 32 + ch * 8) =
                *(const half8*)&hs[rl * H_STRIDE + i * 32 + ch * 8];
    }
}

// ------- kernel 3: persistent per-edge fused MLP, 32 edges/wave -------
__global__ __launch_bounds__(512, 4) void edge_kernel(const int* __restrict__ ei,
                                                      const unsigned char* __restrict__ ws,
                                                      float* __restrict__ out) {
    __shared__ __align__(16) _Float16 w1s[128 * H_STRIDE];   // 34816 B
    __shared__ __align__(16) _Float16 w2s[64 * H_STRIDE];    // 17408 B
    __shared__ __align__(16) _Float16 hc[8][16 * HC_STRIDE]; // 10240 B
    __shared__ float b0s[128], b1s[128], b2s[64];            // total 63744 B

    const _Float16* __restrict__ z    = (const _Float16*)(ws + WS_Z);
    const _Float16* __restrict__ wt1g = (const _Float16*)(ws + WS_W1);
    const _Float16* __restrict__ wt2g = (const _Float16*)(ws + WS_W2);

    {   // stage weights once per (persistent) block
        int t = threadIdx.x;
        #pragma unroll
        for (int it = 0; it < 4; ++it) {
            int c = t + it * 512;
            int row = c >> 4, cc = c & 15;
            *(half8*)&w1s[row * H_STRIDE + cc * 8] = *(const half8*)&wt1g[row * 128 + cc * 8];
        }
        #pragma unroll
        for (int it = 0; it < 2; ++it) {
            int c = t + it * 512;
            int row = c >> 4, cc = c & 15;
            *(half8*)&w2s[row * H_STRIDE + cc * 8] = *(const half8*)&wt2g[row * 128 + cc * 8];
        }
        if (t < 128) {
            b0s[t] = *(const float*)(ws + WS_B0 + t * 4);
            b1s[t] = *(const float*)(ws + WS_B1 + t * 4);
        } else if (t < 192) {
            b2s[t - 128] = *(const float*)(ws + WS_B2 + (size_t)(t - 128) * 4);
        }
    }
    __syncthreads();

    const int wave = threadIdx.x >> 6, lane = threadIdx.x & 63;
    const int cl = lane & 15, q = lane >> 4;
    _Float16* hw = &hc[wave][0];

    int tile = blockIdx.x;
    // indices for first tile (ei is int32: [2][E])
    int s0, d0, s1, d1;
    {
        int r = tile * 256 + wave * 32 + cl;
        s0 = ei[r];           d0 = ei[N_EDGES + r];
        s1 = ei[r + 16];      d1 = ei[N_EDGES + r + 16];
    }

    while (tile < NT) {
        const int next = tile + GRID;
        int ns0 = s0, nd0 = d0, ns1 = s1, nd1 = d1;
        if (next < NT) {      // prefetch next tile's indices (uniform branch)
            int r = next * 256 + wave * 32 + cl;
            ns0 = ei[r];      nd0 = ei[N_EDGES + r];
            ns1 = ei[r + 16]; nd1 = ei[N_EDGES + r + 16];
        }

        const int eb = tile * 256 + wave * 32;

        // gather: h0 = leaky(z[s]+z[d]+b0) built directly as A-frags (2 halves)
        const _Float16* zs0 = z + (size_t)s0 * 128;
        const _Float16* zd0 = z + (size_t)d0 * 128;
        const _Float16* zs1 = z + (size_t)s1 * 128;
        const _Float16* zd1 = z + (size_t)d1 * 128;

        half8 a1lo[4], a1hi[4];
        #pragma unroll
        for (int ks = 0; ks < 4; ++ks) {
            half8 u = *(const half8*)(zs0 + ks * 32 + q * 8);
            half8 v = *(const half8*)(zd0 + ks * 32 + q * 8);
            half8 u2 = *(const half8*)(zs1 + ks * 32 + q * 8);
            half8 v2 = *(const half8*)(zd1 + ks * 32 + q * 8);
            floatx4 bA = *(const floatx4*)&b0s[ks * 32 + q * 8];
            floatx4 bB = *(const floatx4*)&b0s[ks * 32 + q * 8 + 4];
            #pragma unroll
            for (int j = 0; j < 4; ++j) {
                a1lo[ks][j]     = (_Float16)leaky((float)u[j]      + (float)v[j]      + bA[j]);
                a1lo[ks][4 + j] = (_Float16)leaky((float)u[4 + j]  + (float)v[4 + j]  + bB[j]);
                a1hi[ks][j]     = (_Float16)leaky((float)u2[j]     + (float)v2[j]     + bA[j]);
                a1hi[ks][4 + j] = (_Float16)leaky((float)u2[4 + j] + (float)v2[4 + j] + bB[j]);
            }
        }

        floatx4 acc2lo[4], acc2hi[4];
        #pragma unroll
        for (int n2 = 0; n2 < 4; ++n2) {
            acc2lo[n2] = (floatx4){0.f, 0.f, 0.f, 0.f};
            acc2hi[n2] = (floatx4){0.f, 0.f, 0.f, 0.f};
        }

        #pragma unroll
        for (int ks = 0; ks < 4; ++ks) {
            floatx4 kc[2];    // hi-half layer-1 outputs held in regs
            #pragma unroll
            for (int nn = 0; nn < 2; ++nn) {
                const int n = ks * 2 + nn;
                floatx4 c0 = {0.f, 0.f, 0.f, 0.f};
                floatx4 c1 = {0.f, 0.f, 0.f, 0.f};
                #pragma unroll
                for (int kk = 0; kk < 4; ++kk) {
                    half8 b = *(const half8*)&w1s[(n * 16 + cl) * H_STRIDE + kk * 32 + q * 8];
                    c0 = __builtin_amdgcn_mfma_f32_16x16x32_f16(a1lo[kk], b, c0, 0, 0, 0);
                    c1 = __builtin_amdgcn_mfma_f32_16x16x32_f16(a1hi[kk], b, c1, 0, 0, 0);
                }
                const float bb = b1s[n * 16 + cl];
                #pragma unroll
                for (int rr = 0; rr < 4; ++rr)
                    hw[(q * 4 + rr) * HC_STRIDE + nn * 16 + cl] = (_Float16)leaky(c0[rr] + bb);
                kc[nn] = c1;
            }
            // C-layout -> A-layout round trip (lo half), then reuse buffer for hi
            half8 a2lo = *(const half8*)&hw[cl * HC_STRIDE + q * 8];
            #pragma unroll
            for (int nn = 0; nn < 2; ++nn) {
                const float bb = b1s[(ks * 2 + nn) * 16 + cl];
                #pragma unroll
                for (int rr = 0; rr < 4; ++rr)
                    hw[(q * 4 + rr) * HC_STRIDE + nn * 16 + cl] = (_Float16)leaky(kc[nn][rr] + bb);
            }
            half8 a2hi = *(const half8*)&hw[cl * HC_STRIDE + q * 8];

            #pragma unroll
            for (int n2 = 0; n2 < 4; ++n2) {
                half8 b = *(const half8*)&w2s[(n2 * 16 + cl) * H_STRIDE + ks * 32 + q * 8];
                acc2lo[n2] = __builtin_amdgcn_mfma_f32_16x16x32_f16(a2lo, b, acc2lo[n2], 0, 0, 0);
                acc2hi[n2] = __builtin_amdgcn_mfma_f32_16x16x32_f16(a2hi, b, acc2hi[n2], 0, 0, 0);
            }
        }

        #pragma unroll
        for (int n2 = 0; n2 < 4; ++n2) {
            const float bb = b2s[n2 * 16 + cl];
            #pragma unroll
            for (int rr = 0; rr < 4; ++rr) {
                out[(size_t)(eb + q * 4 + rr) * 64 + n2 * 16 + cl]      = leaky(acc2lo[n2][rr] + bb);
                out[(size_t)(eb + 16 + q * 4 + rr) * 64 + n2 * 16 + cl] = leaky(acc2hi[n2][rr] + bb);
            }
        }

        tile = next;
        s0 = ns0; d0 = nd0; s1 = ns1; d1 = nd1;
    }
}

extern "C" void kernel_launch(void* const* d_in, const int* in_sizes, int n_in,
                              void* d_out, int out_size, void* d_ws, size_t ws_size,
                              hipStream_t stream) {
    const float* x  = (const float*)d_in[0];
    const int*   ei = (const int*)d_in[1];     // int inputs arrive as int32
    const float* W0 = (const float*)d_in[2];
    const float* b0 = (const float*)d_in[3];
    const float* W1 = (const float*)d_in[4];
    const float* b1 = (const float*)d_in[5];
    const float* W2 = (const float*)d_in[6];
    const float* b2 = (const float*)d_in[7];
    float* out = (float*)d_out;
    unsigned char* ws = (unsigned char*)d_ws;

    wprep_kernel<<<33, 1024, 0, stream>>>(W0, W1, W2, b0, b1, b2, ws);
    z_kernel<<<(N_NODES + 127) / 128, 512, 0, stream>>>(x, ws);
    edge_kernel<<<GRID, 512, 0, stream>>>(ei, ws, out);
}